// Round 1
// baseline (296.464 us; speedup 1.0000x reference)
//
#include <hip/hip_runtime.h>

#define BATCH   65536
#define IN_DIM  784
#define HDIM    20
#define NCLS    10

#define SPB     64          // samples per block
#define THREADS 256         // 4 waves
#define KSPLIT  4
#define KCHUNK  (IN_DIM / KSPLIT)   // 196

// sorted(set(row))[:2] -> (e0, e1, mask). mask=0 when only one unique module.
__device__ __forceinline__ void route(const int* pw, bool is64, int row,
                                      int& e0, int& e1, float& m) {
    int v0, v1, v2;
    if (is64) {
        v0 = pw[(row * 3 + 0) * 2];
        v1 = pw[(row * 3 + 1) * 2];
        v2 = pw[(row * 3 + 2) * 2];
    } else {
        v0 = pw[row * 3 + 0];
        v1 = pw[row * 3 + 1];
        v2 = pw[row * 3 + 2];
    }
    int lo  = min(v0, min(v1, v2));
    int hi  = max(v0, max(v1, v2));
    int mid = v0 + v1 + v2 - lo - hi;
    e0 = lo;
    if (mid != lo)     { e1 = mid; m = 1.0f; }
    else if (hi != lo) { e1 = hi;  m = 1.0f; }
    else               { e1 = lo;  m = 0.0f; }
}

__global__ __launch_bounds__(THREADS)
void pathnet_kernel(const float* __restrict__ x,
                    const float* __restrict__ W1, const float* __restrict__ b1,
                    const float* __restrict__ W2, const float* __restrict__ b2,
                    const float* __restrict__ W3, const float* __restrict__ b3,
                    const float* __restrict__ Wl, const float* __restrict__ bl,
                    const int*   __restrict__ pathway,
                    float* __restrict__ out)
{
    // partial: [4 waves][40 outs][64 samples]  (stride 64 -> conflict-free)
    __shared__ float smem[KSPLIT * 2 * HDIM * SPB];   // 10240 floats = 40 KB
    float* partial = smem;
    float* h_a = smem;                                 // aliased after barrier
    __shared__ float h_b[SPB * 21];                    // pad 21: gcd(21,32)=1

    const int t    = threadIdx.x;
    const int lane = t & 63;
    // force wave id into an SGPR so W addresses are provably wave-uniform
    const int wave = __builtin_amdgcn_readfirstlane(t >> 6);   // 0..3

    // ---- routing (redundant per-thread; trivial) ----
    // int64 sniff: high words of first 4 values are zero (indices 1,3,5,7
    // are within bounds for both layouts).
    bool is64 = ((pathway[1] | pathway[3] | pathway[5] | pathway[7]) == 0);
    int e10, e11, e20, e21, e30, e31;
    float m1, m2, m3;
    route(pathway, is64, 0, e10, e11, m1);
    route(pathway, is64, 1, e20, e21, m2);
    route(pathway, is64, 2, e30, e31, m3);
    e10 = __builtin_amdgcn_readfirstlane(e10);
    e11 = __builtin_amdgcn_readfirstlane(e11);
    e20 = __builtin_amdgcn_readfirstlane(e20);
    e21 = __builtin_amdgcn_readfirstlane(e21);
    e30 = __builtin_amdgcn_readfirstlane(e30);
    e31 = __builtin_amdgcn_readfirstlane(e31);

    // ---- layer 1: each wave owns a 196-wide K slice, all 40 (2x20) outputs ----
    float acc[2 * HDIM];
#pragma unroll
    for (int i = 0; i < 2 * HDIM; ++i) acc[i] = 0.0f;

    const float* w0 = W1 + (size_t)e10 * HDIM * IN_DIM;
    const float* w1 = W1 + (size_t)e11 * HDIM * IN_DIM;
    const size_t srow = (size_t)blockIdx.x * SPB + lane;
    const float* xr = x + srow * IN_DIM + wave * KCHUNK;

    for (int i = 0; i < KCHUNK / 4; ++i) {            // 49 iters
        float4 xv = reinterpret_cast<const float4*>(xr)[i];
        const int k = wave * KCHUNK + i * 4;          // wave-uniform
#pragma unroll
        for (int o = 0; o < HDIM; ++o) {
            float4 a = *reinterpret_cast<const float4*>(w0 + o * IN_DIM + k);
            float4 b = *reinterpret_cast<const float4*>(w1 + o * IN_DIM + k);
            acc[o]        += xv.x * a.x + xv.y * a.y + xv.z * a.z + xv.w * a.w;
            acc[HDIM + o] += xv.x * b.x + xv.y * b.y + xv.z * b.z + xv.w * b.w;
        }
    }

#pragma unroll
    for (int o = 0; o < 2 * HDIM; ++o)
        partial[(wave * 2 * HDIM + o) * SPB + lane] = acc[o];
    __syncthreads();

    // ---- reduce partials -> h1 (each wave handles 5 of the 20 h-units) ----
    float hreg[5];
#pragma unroll
    for (int j = 0; j < 5; ++j) {
        const int o = wave * 5 + j;
        float p0 = 0.0f, p1 = 0.0f;
#pragma unroll
        for (int w = 0; w < KSPLIT; ++w) {
            p0 += partial[(w * 2 * HDIM + o) * SPB + lane];
            p1 += partial[(w * 2 * HDIM + HDIM + o) * SPB + lane];
        }
        float r0 = fmaxf(p0 + b1[e10 * HDIM + o], 0.0f);
        float r1 = fmaxf(p1 + b1[e11 * HDIM + o], 0.0f);
        hreg[j] = r0 + m1 * r1;
    }
    __syncthreads();                 // all partial reads done before aliasing
#pragma unroll
    for (int j = 0; j < 5; ++j)
        h_a[lane * 21 + wave * 5 + j] = hreg[j];
    __syncthreads();

    // ---- layer 2: h_a -> h_b ----
#pragma unroll
    for (int j = 0; j < 5; ++j) {
        const int o = wave * 5 + j;
        float a0 = 0.0f, a1 = 0.0f;
#pragma unroll
        for (int c = 0; c < HDIM; ++c) {
            float hv = h_a[lane * 21 + c];
            a0 += hv * W2[((size_t)e20 * HDIM + o) * HDIM + c];
            a1 += hv * W2[((size_t)e21 * HDIM + o) * HDIM + c];
        }
        hreg[j] = fmaxf(a0 + b2[e20 * HDIM + o], 0.0f)
                + m2 * fmaxf(a1 + b2[e21 * HDIM + o], 0.0f);
    }
#pragma unroll
    for (int j = 0; j < 5; ++j)
        h_b[lane * 21 + wave * 5 + j] = hreg[j];
    __syncthreads();

    // ---- layer 3: h_b -> h_a ----
#pragma unroll
    for (int j = 0; j < 5; ++j) {
        const int o = wave * 5 + j;
        float a0 = 0.0f, a1 = 0.0f;
#pragma unroll
        for (int c = 0; c < HDIM; ++c) {
            float hv = h_b[lane * 21 + c];
            a0 += hv * W3[((size_t)e30 * HDIM + o) * HDIM + c];
            a1 += hv * W3[((size_t)e31 * HDIM + o) * HDIM + c];
        }
        hreg[j] = fmaxf(a0 + b3[e30 * HDIM + o], 0.0f)
                + m3 * fmaxf(a1 + b3[e31 * HDIM + o], 0.0f);
    }
    __syncthreads();                 // layer-2 reads of h_a are done
#pragma unroll
    for (int j = 0; j < 5; ++j)
        h_a[lane * 21 + wave * 5 + j] = hreg[j];
    __syncthreads();

    // ---- readout: out[s][c] = h3 . Wl[c] + bl[c], coalesced stores ----
#pragma unroll
    for (int i = 0; i < 3; ++i) {
        const int idx = i * THREADS + t;
        if (idx < SPB * NCLS) {
            const int ss = idx / NCLS;
            const int c  = idx % NCLS;
            float v = bl[c];
#pragma unroll
            for (int o = 0; o < HDIM; ++o)
                v += h_a[ss * 21 + o] * Wl[c * HDIM + o];
            out[((size_t)blockIdx.x * SPB + ss) * NCLS + c] = v;
        }
    }
}

extern "C" void kernel_launch(void* const* d_in, const int* in_sizes, int n_in,
                              void* d_out, int out_size, void* d_ws, size_t ws_size,
                              hipStream_t stream) {
    const float* x  = (const float*)d_in[0];
    const float* W1 = (const float*)d_in[1];
    const float* b1 = (const float*)d_in[2];
    const float* W2 = (const float*)d_in[3];
    const float* b2 = (const float*)d_in[4];
    const float* W3 = (const float*)d_in[5];
    const float* b3 = (const float*)d_in[6];
    const float* Wl = (const float*)d_in[7];
    const float* bl = (const float*)d_in[8];
    const int*   pw = (const int*)d_in[9];
    float* out = (float*)d_out;

    dim3 grid(BATCH / SPB);   // 1024 blocks
    pathnet_kernel<<<grid, THREADS, 0, stream>>>(x, W1, b1, W2, b2,
                                                 W3, b3, Wl, bl, pw, out);
}